// Round 20
// baseline (444.590 us; speedup 1.0000x reference)
//
#include <hip/hip_runtime.h>
#include <hip/hip_fp16.h>
#include <cmath>

#define NLEV 16
#define HASH_START 12               // levels >= 12 use spatial hash ((r+1)^2 > 2^19)
#define HMASK ((1u << 19) - 1u)     // hash level size is exactly 2^19
#define HASH_PRIME 2654435761u
#define LDS_WORDS 14160             // offset[6]: entries of levels 0-5 (host-guarded)

typedef float    f4 __attribute__((ext_vector_type(4)));
typedef unsigned u4 __attribute__((ext_vector_type(4)));

struct LvlC {
  float scale[NLEV];
  unsigned stride[NLEV];   // res + 1
  unsigned offset[NLEV];   // cumulative param offset (multiple of 8)
};

__device__ __forceinline__ float2 h2f(unsigned u) {
  return __half22float2(__builtin_bit_cast(__half2, u));
}

// ---- pass 0: fp32 tables -> fp16 copies in ws ----
__global__ __launch_bounds__(256) void k_convert(
    const float2* __restrict__ t0, const float2* __restrict__ t1,
    const float2* __restrict__ t2, unsigned* __restrict__ dst, unsigned total)
{
  unsigned g = blockIdx.x * 256 + threadIdx.x;
  unsigned stp = gridDim.x * 256;
  unsigned tot3 = 3u * total;
  for (unsigned e = g; e < tot3; e += stp) {
    const float2* src; unsigned i = e;
    if (i < total)            { src = t0; }
    else if (i < 2u * total)  { src = t1; i -= total; }
    else                      { src = t2; i -= 2u * total; }
    float2 v = src[i];
    __half2 h = __floats2half2_rn(v.x, v.y);
    __builtin_nontemporal_store(__builtin_bit_cast(unsigned, h), dst + e);
  }
}

// even-x0 trick: (x0+1)^hy == (x0^hy)^1 when x0 even -> aligned uint2 pair
__device__ __forceinline__ void hash_row(
    const unsigned* __restrict__ tp, unsigned x0, unsigned hy,
    unsigned& g0, unsigned& g1)
{
  unsigned a0 = (x0 ^ hy) & HMASK;
  if ((x0 & 1u) == 0u) {
    uint2 v = *reinterpret_cast<const uint2*>(tp + (a0 & ~1u));
    bool hi = (a0 & 1u) != 0u;
    g0 = hi ? v.y : v.x;
    g1 = hi ? v.x : v.y;
  } else {
    g0 = tp[a0];
    g1 = tp[((x0 + 1u) ^ hy) & HMASK];
  }
}

// ---- final-type block body: levels 0-11 for 512 points, writes row[0,96) ----
__device__ __forceinline__ void final_block(
    int fb, int tid, unsigned* lds,
    const float* __restrict__ pts, const unsigned* __restrict__ tab,
    float* __restrict__ out, const LvlC& lc, unsigned total)
{
  int i = fb * 512 + tid;

  float u0 = (pts[3 * i + 0] + 1.f) * .5f;
  float u1 = (pts[3 * i + 1] + 1.f) * .5f;
  float u2 = (pts[3 * i + 2] + 1.f) * .5f;
  const float ua[3] = {u0, u0, u1}, ub[3] = {u1, u2, u2};

  float res[24];                  // [0,12) lvl0-5 | [12,24) lvl6-11
#pragma unroll
  for (int j = 0; j < 12; ++j) res[j] = 0.f;

  uint2 gd[2][3][2];              // dense prefetch (data only; fracs recomputed)

#pragma unroll 1
  for (int p = 0; p < 3; ++p) {
    if (p) __syncthreads();
    const u4* src = reinterpret_cast<const u4*>(tab + (size_t)p * total);
    for (unsigned e = tid; e < LDS_WORDS / 4; e += 512)
      reinterpret_cast<u4*>(lds)[e] = src[e];
    // issue dense group p (levels 6+2p, 7+2p)
#pragma unroll
    for (int h = 0; h < 2; ++h) {
      const int l = 6 + 2 * p + h;
      const float sc = lc.scale[l];
      const unsigned st = lc.stride[l], o = lc.offset[l];
#pragma unroll
      for (int q = 0; q < 3; ++q) {
        float px = ua[q] * sc + .5f, py = ub[q] * sc + .5f;
        unsigned i00 = (unsigned)floorf(px) + (unsigned)floorf(py) * st + o;
        const unsigned* tp = tab + (size_t)q * total;
        gd[h][q][0] = *reinterpret_cast<const uint2*>(tp + i00);
        gd[h][q][1] = *reinterpret_cast<const uint2*>(tp + i00 + st);
      }
    }
    __syncthreads();               // drains staging + dense queue together
#pragma unroll
    for (int l = 0; l < 6; ++l) {
      const float sc = lc.scale[l];
      const unsigned st = lc.stride[l], o = lc.offset[l];
      float px = ua[p] * sc + .5f, py = ub[p] * sc + .5f;
      float fx = floorf(px), fy = floorf(py);
      float x = px - fx, y = py - fy;
      unsigned i00 = (unsigned)fx + (unsigned)fy * st + o;
      float2 f00 = h2f(lds[i00]),      f10 = h2f(lds[i00 + 1]);
      float2 f01 = h2f(lds[i00 + st]), f11 = h2f(lds[i00 + st + 1]);
      float w00 = (1.f - x) * (1.f - y), w10 = x * (1.f - y);
      float w01 = (1.f - x) * y,          w11 = x * y;
      res[2 * l + 0] += w00 * f00.x + w10 * f10.x + w01 * f01.x + w11 * f11.x;
      res[2 * l + 1] += w00 * f00.y + w10 * f10.y + w01 * f01.y + w11 * f11.y;
    }
    // consume dense group p (fracs recomputed)
#pragma unroll
    for (int h = 0; h < 2; ++h) {
      const int l = 6 + 2 * p + h;
      const float sc = lc.scale[l];
      float s0 = 0.f, s1 = 0.f;
#pragma unroll
      for (int q = 0; q < 3; ++q) {
        float px = ua[q] * sc + .5f, py = ub[q] * sc + .5f;
        float x = px - floorf(px), y = py - floorf(py);
        float w00 = (1.f - x) * (1.f - y), w10 = x * (1.f - y);
        float w01 = (1.f - x) * y,          w11 = x * y;
        float2 f00 = h2f(gd[h][q][0].x), f10 = h2f(gd[h][q][0].y);
        float2 f01 = h2f(gd[h][q][1].x), f11 = h2f(gd[h][q][1].y);
        s0 += w00 * f00.x + w10 * f10.x + w01 * f01.x + w11 * f11.x;
        s1 += w00 * f00.y + w10 * f10.y + w01 * f01.y + w11 * f11.y;
      }
      res[12 + 4 * p + 2 * h + 0] = s0;
      res[12 + 4 * p + 2 * h + 1] = s1;
    }
  }

  float4* o4 = (float4*)(out + (size_t)i * 32);   // row[0,96): 6 aligned float4
#pragma unroll
  for (int j = 0; j < 6; ++j)
    o4[j] = make_float4(res[4 * j], res[4 * j + 1], res[4 * j + 2], res[4 * j + 3]);
}

// ---- hash-type block body: levels 12-15 for 2x512 points, writes row[96,128) ----
__device__ __forceinline__ void hash_block(
    int hb, int tid,
    const float* __restrict__ pts, const unsigned* __restrict__ tab,
    float* __restrict__ out, const LvlC& lc, unsigned total, int half)
{
  int t = hb * 512 + tid;
  const int idx[2] = {t, t + half};

  float ua[2][3], ub[2][3];
#pragma unroll
  for (int k = 0; k < 2; ++k) {
    float u0 = (pts[3 * idx[k] + 0] + 1.f) * .5f;
    float u1 = (pts[3 * idx[k] + 1] + 1.f) * .5f;
    float u2 = (pts[3 * idx[k] + 2] + 1.f) * .5f;
    ua[k][0] = u0; ub[k][0] = u1;
    ua[k][1] = u0; ub[k][1] = u2;
    ua[k][2] = u1; ub[k][2] = u2;
  }

  float acc[2][8];                 // per point: levels 12-15 x 2ch

#pragma unroll 1
  for (int l = HASH_START; l < NLEV; ++l) {
    const float sc = lc.scale[l];
    const unsigned o = lc.offset[l];
    unsigned g[2][3][4];
    // issue both points x 3 planes (24 gathers in flight)
#pragma unroll
    for (int k = 0; k < 2; ++k)
#pragma unroll
      for (int q = 0; q < 3; ++q) {
        float px = ua[k][q] * sc + .5f, py = ub[k][q] * sc + .5f;
        unsigned x0 = (unsigned)floorf(px), y0 = (unsigned)floorf(py);
        unsigned hy0 = y0 * HASH_PRIME, hy1 = hy0 + HASH_PRIME;
        const unsigned* tp = tab + (size_t)q * total + o;
        hash_row(tp, x0, hy0, g[k][q][0], g[k][q][1]);
        hash_row(tp, x0, hy1, g[k][q][2], g[k][q][3]);
      }
#pragma unroll
    for (int k = 0; k < 2; ++k) {
      float s0 = 0.f, s1 = 0.f;
#pragma unroll
      for (int q = 0; q < 3; ++q) {
        float px = ua[k][q] * sc + .5f, py = ub[k][q] * sc + .5f;
        float x = px - floorf(px), y = py - floorf(py);
        float w00 = (1.f - x) * (1.f - y), w10 = x * (1.f - y);
        float w01 = (1.f - x) * y,          w11 = x * y;
        float2 f00 = h2f(g[k][q][0]), f10 = h2f(g[k][q][1]);
        float2 f01 = h2f(g[k][q][2]), f11 = h2f(g[k][q][3]);
        s0 += w00 * f00.x + w10 * f10.x + w01 * f01.x + w11 * f11.x;
        s1 += w00 * f00.y + w10 * f10.y + w01 * f01.y + w11 * f11.y;
      }
      acc[k][2 * (l - HASH_START) + 0] = s0;
      acc[k][2 * (l - HASH_START) + 1] = s1;
    }
  }

#pragma unroll
  for (int k = 0; k < 2; ++k) {
    float4* o4 = (float4*)(out + (size_t)idx[k] * 32 + 24);  // row[96,128): 2 float4
    o4[0] = make_float4(acc[k][0], acc[k][1], acc[k][2], acc[k][3]);
    o4[1] = make_float4(acc[k][4], acc[k][5], acc[k][6], acc[k][7]);
  }
}

// ---- heterogeneous kernel: bid%3<2 -> final-type, ==2 -> hash-type.
//      2:1 interleave co-schedules both types on every CU: hash waves grind
//      the TA while final waves sit at staging barriers. Disjoint row bytes
//      -> no dependency, no slices. ----
__global__ __launch_bounds__(512) void k_mix(
    const float* __restrict__ pts, const unsigned* __restrict__ tab,
    float* __restrict__ out, LvlC lc, unsigned total, int n)
{
  __shared__ unsigned lds[LDS_WORDS];
  unsigned bid = blockIdx.x;
  unsigned grp = bid / 3, r = bid % 3;
  if (r == 2) {
    hash_block(grp, threadIdx.x, pts, tab, out, lc, total, n >> 1);
  } else {
    final_block(grp * 2 + r, threadIdx.x, lds, pts, tab, out, lc, total);
  }
}

// ---- fallback: monolithic fp32 (guards failed) ----
__global__ __launch_bounds__(256) void k_fallback(
    const float* __restrict__ pts, const float2* __restrict__ txy,
    const float2* __restrict__ txz, const float2* __restrict__ tyz,
    float* __restrict__ out, LvlC lc, int n)
{
  int i = blockIdx.x * 256 + threadIdx.x;
  if (i >= n) return;
  float u0 = (pts[3 * i + 0] + 1.f) * .5f;
  float u1 = (pts[3 * i + 1] + 1.f) * .5f;
  float u2 = (pts[3 * i + 2] + 1.f) * .5f;
  const float ua[3] = {u0, u0, u1}, ub[3] = {u1, u2, u2};
  const float2* tabs[3] = {txy, txz, tyz};
  float acc[32];
#pragma unroll
  for (int j = 0; j < 32; ++j) acc[j] = 0.f;
#pragma unroll
  for (int l = 0; l < NLEV; ++l) {
    const float sc = lc.scale[l];
    const unsigned o = lc.offset[l], s = lc.stride[l];
#pragma unroll
    for (int p = 0; p < 3; ++p) {
      const float2* t = tabs[p];
      float px = ua[p] * sc + .5f, py = ub[p] * sc + .5f;
      float fx = floorf(px), fy = floorf(py);
      float rx = px - fx, ry = py - fy;
      unsigned x0 = (unsigned)fx, y0 = (unsigned)fy;
      float w00 = (1.f - rx) * (1.f - ry), w10 = rx * (1.f - ry);
      float w01 = (1.f - rx) * ry,          w11 = rx * ry;
      float2 f00, f10, f01, f11;
      if (l >= HASH_START) {
        unsigned hy0 = y0 * HASH_PRIME, hy1 = hy0 + HASH_PRIME;
        f00 = t[o + ((x0 ^ hy0) & HMASK)];
        f10 = t[o + (((x0 + 1u) ^ hy0) & HMASK)];
        f01 = t[o + ((x0 ^ hy1) & HMASK)];
        f11 = t[o + (((x0 + 1u) ^ hy1) & HMASK)];
      } else {
        unsigned i00 = x0 + y0 * s;
        float4 r0 = *reinterpret_cast<const float4*>(t + o + i00);
        float4 r1 = *reinterpret_cast<const float4*>(t + o + i00 + s);
        f00 = make_float2(r0.x, r0.y); f10 = make_float2(r0.z, r0.w);
        f01 = make_float2(r1.x, r1.y); f11 = make_float2(r1.z, r1.w);
      }
      acc[2 * l + 0] += w00 * f00.x + w10 * f10.x + w01 * f01.x + w11 * f11.x;
      acc[2 * l + 1] += w00 * f00.y + w10 * f10.y + w01 * f01.y + w11 * f11.y;
    }
  }
  float4* o4 = (float4*)(out + (size_t)i * 32);
#pragma unroll
  for (int j = 0; j < 8; ++j)
    o4[j] = make_float4(acc[4 * j], acc[4 * j + 1], acc[4 * j + 2], acc[4 * j + 3]);
}

static unsigned compute_levels(LvlC* lc)
{
  // Mirrors Python _level_constants() with identical double-precision ops.
  const double pls = std::pow(2.0, std::log2(2048.0 / 16.0) / 15.0);
  unsigned long long off = 0;
  for (int l = 0; l < NLEV; ++l) {
    double s = 16.0 * std::pow(pls, (double)l) - 1.0;
    lc->scale[l] = (float)s;
    long long r = (long long)std::ceil(s) + 1;
    long long dense = (r + 1) * (r + 1);
    long long sz = dense < (1LL << 19) ? dense : (1LL << 19);
    sz = ((sz + 7) / 8) * 8;
    lc->stride[l] = (unsigned)(r + 1);
    lc->offset[l] = (unsigned)off;
    off += (unsigned long long)sz;
  }
  return (unsigned)off;
}

extern "C" void kernel_launch(void* const* d_in, const int* in_sizes, int n_in,
                              void* d_out, int out_size, void* d_ws, size_t ws_size,
                              hipStream_t stream) {
  const float*  pts = (const float*)d_in[0];
  const float2* txy = (const float2*)d_in[1];
  const float2* txz = (const float2*)d_in[2];
  const float2* tyz = (const float2*)d_in[3];
  float* out = (float*)d_out;
  int n = in_sizes[0] / 3;  // 1048576 points

  LvlC lc;
  unsigned total = compute_levels(&lc);

  size_t need = (size_t)3 * total * 4;

  // need n%1024==0: final blocks cover n/512, hash blocks cover (n/2)/512
  bool ok = (n % 1024 == 0) && (lc.offset[6] == LDS_WORDS) && (ws_size >= need);
  for (int l = HASH_START; l < NLEV; ++l) {
    unsigned sz = ((l + 1 < NLEV) ? lc.offset[l + 1] : total) - lc.offset[l];
    ok = ok && (sz == (1u << 19));
  }

  int block = 256;
  int grid = (n + block - 1) / block;
  if (!ok) {
    k_fallback<<<grid, block, 0, stream>>>(pts, txy, txz, tyz, out, lc, n);
    return;
  }

  unsigned* tab16 = (unsigned*)d_ws;
  k_convert<<<2048, 256, 0, stream>>>(txy, txz, tyz, tab16, total);
  // grid: 3 * (n/1024) blocks; per triple {final, final, hash}
  int nmix = 3 * (n / 1024);
  k_mix<<<nmix, 512, 0, stream>>>(pts, tab16, out, lc, total, n);
}

// Round 21
// 386.476 us; speedup vs baseline: 1.1504x; 1.1504x over previous
//
#include <hip/hip_runtime.h>
#include <hip/hip_fp16.h>
#include <cmath>

#define NLEV 16
#define HASH_START 12               // levels >= 12 use spatial hash ((r+1)^2 > 2^19)
#define HMASK ((1u << 19) - 1u)     // hash level size is exactly 2^19
#define HASH_PRIME 2654435761u
#define LDS_WORDS 14160             // offset[6]: entries of levels 0-5 (host-guarded)

typedef float    f4 __attribute__((ext_vector_type(4)));
typedef unsigned u4 __attribute__((ext_vector_type(4)));

struct LvlC {
  float scale[NLEV];
  unsigned stride[NLEV];   // res + 1
  unsigned offset[NLEV];   // cumulative param offset (multiple of 8)
};

__device__ __forceinline__ float2 h2f(unsigned u) {
  return __half22float2(__builtin_bit_cast(__half2, u));
}

// ---- pass 0: fp32 tables -> fp16 copies in ws ----
__global__ __launch_bounds__(256) void k_convert(
    const float2* __restrict__ t0, const float2* __restrict__ t1,
    const float2* __restrict__ t2, unsigned* __restrict__ dst, unsigned total)
{
  unsigned g = blockIdx.x * 256 + threadIdx.x;
  unsigned stp = gridDim.x * 256;
  unsigned tot3 = 3u * total;
  for (unsigned e = g; e < tot3; e += stp) {
    const float2* src; unsigned i = e;
    if (i < total)            { src = t0; }
    else if (i < 2u * total)  { src = t1; i -= total; }
    else                      { src = t2; i -= 2u * total; }
    float2 v = src[i];
    __half2 h = __floats2half2_rn(v.x, v.y);
    __builtin_nontemporal_store(__builtin_bit_cast(unsigned, h), dst + e);
  }
}

// even-x0 trick: (x0+1)^hy == (x0^hy)^1 when x0 even -> aligned uint2 pair
__device__ __forceinline__ void hash_row(
    const unsigned* __restrict__ tp, unsigned x0, unsigned hy,
    unsigned& g0, unsigned& g1)
{
  unsigned a0 = (x0 ^ hy) & HMASK;
  if ((x0 & 1u) == 0u) {
    uint2 v = *reinterpret_cast<const uint2*>(tp + (a0 & ~1u));
    bool hi = (a0 & 1u) != 0u;
    g0 = hi ? v.y : v.x;
    g1 = hi ? v.x : v.y;
  } else {
    g0 = tp[a0];
    g1 = tp[((x0 + 1u) ^ hy) & HMASK];
  }
}

// ---- one hash level, all 3 planes, 2 pts/thread (R15 exact) ----
__global__ __launch_bounds__(256) void k_hash_lvl(
    const float* __restrict__ pts, const unsigned* __restrict__ tab,
    unsigned* __restrict__ slice, float sc, unsigned o, unsigned total, int half)
{
  int t = blockIdx.x * 256 + threadIdx.x;
  if (t >= half) return;
  const int idx[2] = {t, t + half};

  float ua[2][3], ub[2][3];
#pragma unroll
  for (int k = 0; k < 2; ++k) {
    float u0 = (pts[3 * idx[k] + 0] + 1.f) * .5f;
    float u1 = (pts[3 * idx[k] + 1] + 1.f) * .5f;
    float u2 = (pts[3 * idx[k] + 2] + 1.f) * .5f;
    ua[k][0] = u0; ub[k][0] = u1;
    ua[k][1] = u0; ub[k][1] = u2;
    ua[k][2] = u1; ub[k][2] = u2;
  }

  unsigned g[2][3][4];
  float rx[2][3], ry[2][3];
#pragma unroll
  for (int k = 0; k < 2; ++k)
#pragma unroll
    for (int p = 0; p < 3; ++p) {
      float px = ua[k][p] * sc + .5f, py = ub[k][p] * sc + .5f;
      float fx = floorf(px), fy = floorf(py);
      rx[k][p] = px - fx; ry[k][p] = py - fy;
      unsigned x0 = (unsigned)fx, y0 = (unsigned)fy;
      unsigned hy0 = y0 * HASH_PRIME, hy1 = hy0 + HASH_PRIME;
      const unsigned* tp = tab + (size_t)p * total + o;
      hash_row(tp, x0, hy0, g[k][p][0], g[k][p][1]);
      hash_row(tp, x0, hy1, g[k][p][2], g[k][p][3]);
    }

#pragma unroll
  for (int k = 0; k < 2; ++k) {
    float s0 = 0.f, s1 = 0.f;
#pragma unroll
    for (int p = 0; p < 3; ++p) {
      float x = rx[k][p], y = ry[k][p];
      float w00 = (1.f - x) * (1.f - y), w10 = x * (1.f - y);
      float w01 = (1.f - x) * y,          w11 = x * y;
      float2 f00 = h2f(g[k][p][0]), f10 = h2f(g[k][p][1]);
      float2 f01 = h2f(g[k][p][2]), f11 = h2f(g[k][p][3]);
      s0 += w00 * f00.x + w10 * f10.x + w01 * f01.x + w11 * f11.x;
      s1 += w00 * f00.y + w10 * f10.y + w01 * f01.y + w11 * f11.y;
    }
    __builtin_nontemporal_store(
        __builtin_bit_cast(unsigned, __floats2half2_rn(s0, s1)), slice + idx[k]);
  }
}

// ---- final: R15 structure at 2 pts/thread. Per phase p: {stage plane p +
//      issue dense group p for BOTH points (24 uint2 in flight)} -> barrier
//      -> LDS compute both pts -> consume dense both pts. Fracs recomputed
//      at consume (prefetch holds data only). 4 hash slices merged at end. ----
__global__ __launch_bounds__(512) void k_final(
    const float* __restrict__ pts, const unsigned* __restrict__ tab,
    const unsigned* __restrict__ slices,   // 4 x n, levels 12..15
    float* __restrict__ out, LvlC lc, unsigned total, int n)
{
  __shared__ unsigned lds[LDS_WORDS];
  const int tid = threadIdx.x;
  int half = n >> 1;
  int t = blockIdx.x * 512 + tid;          // half % 512 == 0 (host-guarded)
  const int idx[2] = {t, t + half};

  float u[2][3];
#pragma unroll
  for (int k = 0; k < 2; ++k) {
    u[k][0] = (pts[3 * idx[k] + 0] + 1.f) * .5f;
    u[k][1] = (pts[3 * idx[k] + 1] + 1.f) * .5f;
    u[k][2] = (pts[3 * idx[k] + 2] + 1.f) * .5f;
  }
  // plane coords: a = u[A(p)], b = u[B(p)]; A = {0,0,1}, B = {1,2,2}

  float res[2][24];              // [0,12) lvl0-5 | [12,24) lvl6-11, per point
#pragma unroll
  for (int k = 0; k < 2; ++k)
#pragma unroll
    for (int j = 0; j < 12; ++j) res[k][j] = 0.f;

  uint2 gd[2][2][3][2];          // dense prefetch, data only (48 regs peak)

#pragma unroll 1
  for (int p = 0; p < 3; ++p) {
    const int A = (p == 2) ? 1 : 0, B = (p == 0) ? 1 : 2;
    if (p) __syncthreads();
    const u4* src = reinterpret_cast<const u4*>(tab + (size_t)p * total);
    for (unsigned e = tid; e < LDS_WORDS / 4; e += 512)
      reinterpret_cast<u4*>(lds)[e] = src[e];
    // issue dense group p (levels 6+2p, 7+2p) for both points
#pragma unroll
    for (int k = 0; k < 2; ++k)
#pragma unroll
      for (int h = 0; h < 2; ++h) {
        const int l = 6 + 2 * p + h;
        const float sc = lc.scale[l];
        const unsigned st = lc.stride[l], o = lc.offset[l];
#pragma unroll
        for (int q = 0; q < 3; ++q) {
          const int qa = (q == 2) ? 1 : 0, qb = (q == 0) ? 1 : 2;
          float px = u[k][qa] * sc + .5f, py = u[k][qb] * sc + .5f;
          unsigned i00 = (unsigned)floorf(px) + (unsigned)floorf(py) * st + o;
          const unsigned* tp = tab + (size_t)q * total;
          gd[k][h][q][0] = *reinterpret_cast<const uint2*>(tp + i00);
          gd[k][h][q][1] = *reinterpret_cast<const uint2*>(tp + i00 + st);
        }
      }
    __syncthreads();             // drains staging + dense queues together
    // LDS compute: levels 0-5, plane p, both points
#pragma unroll
    for (int l = 0; l < 6; ++l) {
      const float sc = lc.scale[l];
      const unsigned st = lc.stride[l], o = lc.offset[l];
#pragma unroll
      for (int k = 0; k < 2; ++k) {
        float px = u[k][A] * sc + .5f, py = u[k][B] * sc + .5f;
        float fx = floorf(px), fy = floorf(py);
        float x = px - fx, y = py - fy;
        unsigned i00 = (unsigned)fx + (unsigned)fy * st + o;
        float2 f00 = h2f(lds[i00]),      f10 = h2f(lds[i00 + 1]);
        float2 f01 = h2f(lds[i00 + st]), f11 = h2f(lds[i00 + st + 1]);
        float w00 = (1.f - x) * (1.f - y), w10 = x * (1.f - y);
        float w01 = (1.f - x) * y,          w11 = x * y;
        res[k][2 * l + 0] += w00 * f00.x + w10 * f10.x + w01 * f01.x + w11 * f11.x;
        res[k][2 * l + 1] += w00 * f00.y + w10 * f10.y + w01 * f01.y + w11 * f11.y;
      }
    }
    // consume dense group p (fracs recomputed)
#pragma unroll
    for (int k = 0; k < 2; ++k)
#pragma unroll
      for (int h = 0; h < 2; ++h) {
        const int l = 6 + 2 * p + h;
        const float sc = lc.scale[l];
        float s0 = 0.f, s1 = 0.f;
#pragma unroll
        for (int q = 0; q < 3; ++q) {
          const int qa = (q == 2) ? 1 : 0, qb = (q == 0) ? 1 : 2;
          float px = u[k][qa] * sc + .5f, py = u[k][qb] * sc + .5f;
          float x = px - floorf(px), y = py - floorf(py);
          float w00 = (1.f - x) * (1.f - y), w10 = x * (1.f - y);
          float w01 = (1.f - x) * y,          w11 = x * y;
          float2 f00 = h2f(gd[k][h][q][0].x), f10 = h2f(gd[k][h][q][0].y);
          float2 f01 = h2f(gd[k][h][q][1].x), f11 = h2f(gd[k][h][q][1].y);
          s0 += w00 * f00.x + w10 * f10.x + w01 * f01.x + w11 * f11.x;
          s1 += w00 * f00.y + w10 * f10.y + w01 * f01.y + w11 * f11.y;
        }
        res[k][12 + 4 * p + 2 * h + 0] = s0;
        res[k][12 + 4 * p + 2 * h + 1] = s1;
      }
  }

  // hash slices (levels 12-15) + assemble + full-line row stores
#pragma unroll
  for (int k = 0; k < 2; ++k) {
    unsigned sl[4];
#pragma unroll
    for (int j = 0; j < 4; ++j) sl[j] = slices[(size_t)j * n + idx[k]];
    float v[32];
#pragma unroll
    for (int j = 0; j < 24; ++j) v[j] = res[k][j];
#pragma unroll
    for (int j = 0; j < 4; ++j) {
      float2 f = h2f(sl[j]);
      v[24 + 2 * j] = f.x; v[24 + 2 * j + 1] = f.y;
    }
    float4* o4 = (float4*)(out + (size_t)idx[k] * 32);
#pragma unroll
    for (int j = 0; j < 8; ++j)
      o4[j] = make_float4(v[4 * j], v[4 * j + 1], v[4 * j + 2], v[4 * j + 3]);
  }
}

// ---- fallback: monolithic fp32 (guards failed) ----
__global__ __launch_bounds__(256) void k_fallback(
    const float* __restrict__ pts, const float2* __restrict__ txy,
    const float2* __restrict__ txz, const float2* __restrict__ tyz,
    float* __restrict__ out, LvlC lc, int n)
{
  int i = blockIdx.x * 256 + threadIdx.x;
  if (i >= n) return;
  float u0 = (pts[3 * i + 0] + 1.f) * .5f;
  float u1 = (pts[3 * i + 1] + 1.f) * .5f;
  float u2 = (pts[3 * i + 2] + 1.f) * .5f;
  const float ua[3] = {u0, u0, u1}, ub[3] = {u1, u2, u2};
  const float2* tabs[3] = {txy, txz, tyz};
  float acc[32];
#pragma unroll
  for (int j = 0; j < 32; ++j) acc[j] = 0.f;
#pragma unroll
  for (int l = 0; l < NLEV; ++l) {
    const float sc = lc.scale[l];
    const unsigned o = lc.offset[l], s = lc.stride[l];
#pragma unroll
    for (int p = 0; p < 3; ++p) {
      const float2* t = tabs[p];
      float px = ua[p] * sc + .5f, py = ub[p] * sc + .5f;
      float fx = floorf(px), fy = floorf(py);
      float rx = px - fx, ry = py - fy;
      unsigned x0 = (unsigned)fx, y0 = (unsigned)fy;
      float w00 = (1.f - rx) * (1.f - ry), w10 = rx * (1.f - ry);
      float w01 = (1.f - rx) * ry,          w11 = rx * ry;
      float2 f00, f10, f01, f11;
      if (l >= HASH_START) {
        unsigned hy0 = y0 * HASH_PRIME, hy1 = hy0 + HASH_PRIME;
        f00 = t[o + ((x0 ^ hy0) & HMASK)];
        f10 = t[o + (((x0 + 1u) ^ hy0) & HMASK)];
        f01 = t[o + ((x0 ^ hy1) & HMASK)];
        f11 = t[o + (((x0 + 1u) ^ hy1) & HMASK)];
      } else {
        unsigned i00 = x0 + y0 * s;
        float4 r0 = *reinterpret_cast<const float4*>(t + o + i00);
        float4 r1 = *reinterpret_cast<const float4*>(t + o + i00 + s);
        f00 = make_float2(r0.x, r0.y); f10 = make_float2(r0.z, r0.w);
        f01 = make_float2(r1.x, r1.y); f11 = make_float2(r1.z, r1.w);
      }
      acc[2 * l + 0] += w00 * f00.x + w10 * f10.x + w01 * f01.x + w11 * f11.x;
      acc[2 * l + 1] += w00 * f00.y + w10 * f10.y + w01 * f01.y + w11 * f11.y;
    }
  }
  float4* o4 = (float4*)(out + (size_t)i * 32);
#pragma unroll
  for (int j = 0; j < 8; ++j)
    o4[j] = make_float4(acc[4 * j], acc[4 * j + 1], acc[4 * j + 2], acc[4 * j + 3]);
}

static unsigned compute_levels(LvlC* lc)
{
  // Mirrors Python _level_constants() with identical double-precision ops.
  const double pls = std::pow(2.0, std::log2(2048.0 / 16.0) / 15.0);
  unsigned long long off = 0;
  for (int l = 0; l < NLEV; ++l) {
    double s = 16.0 * std::pow(pls, (double)l) - 1.0;
    lc->scale[l] = (float)s;
    long long r = (long long)std::ceil(s) + 1;
    long long dense = (r + 1) * (r + 1);
    long long sz = dense < (1LL << 19) ? dense : (1LL << 19);
    sz = ((sz + 7) / 8) * 8;
    lc->stride[l] = (unsigned)(r + 1);
    lc->offset[l] = (unsigned)off;
    off += (unsigned long long)sz;
  }
  return (unsigned)off;
}

extern "C" void kernel_launch(void* const* d_in, const int* in_sizes, int n_in,
                              void* d_out, int out_size, void* d_ws, size_t ws_size,
                              hipStream_t stream) {
  const float*  pts = (const float*)d_in[0];
  const float2* txy = (const float2*)d_in[1];
  const float2* txz = (const float2*)d_in[2];
  const float2* tyz = (const float2*)d_in[3];
  float* out = (float*)d_out;
  int n = in_sizes[0] / 3;  // 1048576 points

  LvlC lc;
  unsigned total = compute_levels(&lc);

  size_t tab_bytes = (size_t)3 * total * 4;
  size_t tab_al = (tab_bytes + 255) & ~(size_t)255;
  size_t need = tab_al + (size_t)4 * n * 4;

  bool ok = (n % 1024 == 0) && (lc.offset[6] == LDS_WORDS) && (ws_size >= need);
  for (int l = HASH_START; l < NLEV; ++l) {
    unsigned sz = ((l + 1 < NLEV) ? lc.offset[l + 1] : total) - lc.offset[l];
    ok = ok && (sz == (1u << 19));
  }

  int block = 256;
  int grid = (n + block - 1) / block;
  if (!ok) {
    k_fallback<<<grid, block, 0, stream>>>(pts, txy, txz, tyz, out, lc, n);
    return;
  }

  unsigned* tab16 = (unsigned*)d_ws;
  unsigned* slices = (unsigned*)((char*)d_ws + tab_al);  // 4 x n (levels 12..15)

  int half = n / 2;
  int gridh = half / block;

  k_convert<<<2048, 256, 0, stream>>>(txy, txz, tyz, tab16, total);
  for (int l = HASH_START; l < NLEV; ++l)
    k_hash_lvl<<<gridh, block, 0, stream>>>(pts, tab16, slices + (size_t)(l - 12) * n,
                                            lc.scale[l], lc.offset[l], total, half);
  k_final<<<half / 512, 512, 0, stream>>>(pts, tab16, slices, out, lc, total, n);
}

// Round 22
// 320.836 us; speedup vs baseline: 1.3857x; 1.2046x over previous
//
#include <hip/hip_runtime.h>
#include <hip/hip_fp16.h>
#include <cmath>

#define NLEV 16
#define HASH_START 12               // levels >= 12 use spatial hash ((r+1)^2 > 2^19)
#define HMASK ((1u << 19) - 1u)     // hash level size is exactly 2^19
#define HASH_PRIME 2654435761u
#define LDS_WORDS 14160             // offset[6]: entries of levels 0-5 (host-guarded)

typedef float    f4 __attribute__((ext_vector_type(4)));
typedef unsigned u4 __attribute__((ext_vector_type(4)));

struct LvlC {
  float scale[NLEV];
  unsigned stride[NLEV];   // res + 1
  unsigned offset[NLEV];   // cumulative param offset (multiple of 8)
};

__device__ __forceinline__ float2 h2f(unsigned u) {
  return __half22float2(__builtin_bit_cast(__half2, u));
}

// ---- pass 0: fp32 tables -> fp16 copies in ws ----
__global__ __launch_bounds__(256) void k_convert(
    const float2* __restrict__ t0, const float2* __restrict__ t1,
    const float2* __restrict__ t2, unsigned* __restrict__ dst, unsigned total)
{
  unsigned g = blockIdx.x * 256 + threadIdx.x;
  unsigned stp = gridDim.x * 256;
  unsigned tot3 = 3u * total;
  for (unsigned e = g; e < tot3; e += stp) {
    const float2* src; unsigned i = e;
    if (i < total)            { src = t0; }
    else if (i < 2u * total)  { src = t1; i -= total; }
    else                      { src = t2; i -= 2u * total; }
    float2 v = src[i];
    __half2 h = __floats2half2_rn(v.x, v.y);
    __builtin_nontemporal_store(__builtin_bit_cast(unsigned, h), dst + e);
  }
}

// even-x0 trick: (x0+1)^hy == (x0^hy)^1 when x0 even -> aligned uint2 pair
__device__ __forceinline__ void hash_row(
    const unsigned* __restrict__ tp, unsigned x0, unsigned hy,
    unsigned& g0, unsigned& g1)
{
  unsigned a0 = (x0 ^ hy) & HMASK;
  if ((x0 & 1u) == 0u) {
    uint2 v = *reinterpret_cast<const uint2*>(tp + (a0 & ~1u));
    bool hi = (a0 & 1u) != 0u;
    g0 = hi ? v.y : v.x;
    g1 = hi ? v.x : v.y;
  } else {
    g0 = tp[a0];
    g1 = tp[((x0 + 1u) ^ hy) & HMASK];
  }
}

// ---- one hash level, all 3 planes, 2 pts/thread ----
__global__ __launch_bounds__(256) void k_hash_lvl(
    const float* __restrict__ pts, const unsigned* __restrict__ tab,
    unsigned* __restrict__ slice, float sc, unsigned o, unsigned total, int half)
{
  int t = blockIdx.x * 256 + threadIdx.x;
  if (t >= half) return;
  const int idx[2] = {t, t + half};

  float ua[2][3], ub[2][3];
#pragma unroll
  for (int k = 0; k < 2; ++k) {
    float u0 = (pts[3 * idx[k] + 0] + 1.f) * .5f;
    float u1 = (pts[3 * idx[k] + 1] + 1.f) * .5f;
    float u2 = (pts[3 * idx[k] + 2] + 1.f) * .5f;
    ua[k][0] = u0; ub[k][0] = u1;
    ua[k][1] = u0; ub[k][1] = u2;
    ua[k][2] = u1; ub[k][2] = u2;
  }

  unsigned g[2][3][4];
  float rx[2][3], ry[2][3];
#pragma unroll
  for (int k = 0; k < 2; ++k)
#pragma unroll
    for (int p = 0; p < 3; ++p) {
      float px = ua[k][p] * sc + .5f, py = ub[k][p] * sc + .5f;
      float fx = floorf(px), fy = floorf(py);
      rx[k][p] = px - fx; ry[k][p] = py - fy;
      unsigned x0 = (unsigned)fx, y0 = (unsigned)fy;
      unsigned hy0 = y0 * HASH_PRIME, hy1 = hy0 + HASH_PRIME;
      const unsigned* tp = tab + (size_t)p * total + o;
      hash_row(tp, x0, hy0, g[k][p][0], g[k][p][1]);
      hash_row(tp, x0, hy1, g[k][p][2], g[k][p][3]);
    }

#pragma unroll
  for (int k = 0; k < 2; ++k) {
    float s0 = 0.f, s1 = 0.f;
#pragma unroll
    for (int p = 0; p < 3; ++p) {
      float x = rx[k][p], y = ry[k][p];
      float w00 = (1.f - x) * (1.f - y), w10 = x * (1.f - y);
      float w01 = (1.f - x) * y,          w11 = x * y;
      float2 f00 = h2f(g[k][p][0]), f10 = h2f(g[k][p][1]);
      float2 f01 = h2f(g[k][p][2]), f11 = h2f(g[k][p][3]);
      s0 += w00 * f00.x + w10 * f10.x + w01 * f01.x + w11 * f11.x;
      s1 += w00 * f00.y + w10 * f10.y + w01 * f01.y + w11 * f11.y;
    }
    __builtin_nontemporal_store(
        __builtin_bit_cast(unsigned, __floats2half2_rn(s0, s1)), slice + idx[k]);
  }
}

// ---- final: per plane-phase p: {issue LDS staging + issue dense group p's
//      uint2 gathers} -> barrier (drains both) -> LDS levels 0-5 compute ->
//      consume dense group p. Dense latency hides under staging + LDS work.
//      Then 4 hash slices merged, one full-line row store. ----
__global__ __launch_bounds__(512) void k_final(
    const float* __restrict__ pts, const unsigned* __restrict__ tab,
    const unsigned* __restrict__ slices,   // 4 x n, levels 12..15
    float* __restrict__ out, LvlC lc, unsigned total, int n)
{
  __shared__ unsigned lds[LDS_WORDS];
  int i = blockIdx.x * 512 + threadIdx.x;   // n % 512 == 0 (host-guarded)

  float u0 = (pts[3 * i + 0] + 1.f) * .5f;
  float u1 = (pts[3 * i + 1] + 1.f) * .5f;
  float u2 = (pts[3 * i + 2] + 1.f) * .5f;
  const float ua[3] = {u0, u0, u1}, ub[3] = {u1, u2, u2};

  float res[24];                            // [0..12): levels 0-5; [12..24): levels 6-11
#pragma unroll
  for (int j = 0; j < 12; ++j) res[j] = 0.f;

  // dense group state (one 2-level group live at a time)
  uint2 g[2][3][2];
  float gx[2][3], gy[2][3];

#pragma unroll 1
  for (int p = 0; p < 3; ++p) {
    if (p) __syncthreads();
    // issue staging loads
    const u4* src = reinterpret_cast<const u4*>(tab + (size_t)p * total);
    for (unsigned e = threadIdx.x; e < LDS_WORDS / 4; e += 512)
      reinterpret_cast<u4*>(lds)[e] = src[e];
    // issue dense group p (levels 6+2p, 7+2p) -- grinds in TCP alongside staging
#pragma unroll
    for (int h = 0; h < 2; ++h) {
      const int l = 6 + 2 * p + h;
      const float sc = lc.scale[l];
      const unsigned st = lc.stride[l], o = lc.offset[l];
#pragma unroll
      for (int q = 0; q < 3; ++q) {
        float px = ua[q] * sc + .5f, py = ub[q] * sc + .5f;
        float fx = floorf(px), fy = floorf(py);
        gx[h][q] = px - fx; gy[h][q] = py - fy;
        unsigned i00 = (unsigned)fx + (unsigned)fy * st + o;
        const unsigned* tp = tab + (size_t)q * total;
        g[h][q][0] = *reinterpret_cast<const uint2*>(tp + i00);
        g[h][q][1] = *reinterpret_cast<const uint2*>(tp + i00 + st);
      }
    }
    __syncthreads();   // drains staging stores AND our dense loads together
    // LDS compute: levels 0-5, plane p
#pragma unroll
    for (int l = 0; l < 6; ++l) {
      const float sc = lc.scale[l];
      const unsigned st = lc.stride[l], o = lc.offset[l];
      float px = ua[p] * sc + .5f, py = ub[p] * sc + .5f;
      float fx = floorf(px), fy = floorf(py);
      float x = px - fx, y = py - fy;
      unsigned i00 = (unsigned)fx + (unsigned)fy * st + o;
      float2 f00 = h2f(lds[i00]),      f10 = h2f(lds[i00 + 1]);
      float2 f01 = h2f(lds[i00 + st]), f11 = h2f(lds[i00 + st + 1]);
      float w00 = (1.f - x) * (1.f - y), w10 = x * (1.f - y);
      float w01 = (1.f - x) * y,          w11 = x * y;
      res[2 * l + 0] += w00 * f00.x + w10 * f10.x + w01 * f01.x + w11 * f11.x;
      res[2 * l + 1] += w00 * f00.y + w10 * f10.y + w01 * f01.y + w11 * f11.y;
    }
    // consume dense group p
#pragma unroll
    for (int h = 0; h < 2; ++h) {
      float s0 = 0.f, s1 = 0.f;
#pragma unroll
      for (int q = 0; q < 3; ++q) {
        float x = gx[h][q], y = gy[h][q];
        float w00 = (1.f - x) * (1.f - y), w10 = x * (1.f - y);
        float w01 = (1.f - x) * y,          w11 = x * y;
        float2 f00 = h2f(g[h][q][0].x), f10 = h2f(g[h][q][0].y);
        float2 f01 = h2f(g[h][q][1].x), f11 = h2f(g[h][q][1].y);
        s0 += w00 * f00.x + w10 * f10.x + w01 * f01.x + w11 * f11.x;
        s1 += w00 * f00.y + w10 * f10.y + w01 * f01.y + w11 * f11.y;
      }
      res[12 + 4 * p + 2 * h + 0] = s0;
      res[12 + 4 * p + 2 * h + 1] = s1;
    }
  }

  // hash slices (levels 12-15) + assemble + full-line row store
  unsigned sl[4];
#pragma unroll
  for (int j = 0; j < 4; ++j) sl[j] = slices[(size_t)j * n + i];

  float v[32];
#pragma unroll
  for (int j = 0; j < 24; ++j) v[j] = res[j];
#pragma unroll
  for (int j = 0; j < 4; ++j) {
    float2 f = h2f(sl[j]);
    v[24 + 2 * j] = f.x; v[24 + 2 * j + 1] = f.y;
  }
  float4* o4 = (float4*)(out + (size_t)i * 32);
#pragma unroll
  for (int j = 0; j < 8; ++j)
    o4[j] = make_float4(v[4 * j], v[4 * j + 1], v[4 * j + 2], v[4 * j + 3]);
}

// ---- fallback: monolithic fp32 (guards failed) ----
__global__ __launch_bounds__(256) void k_fallback(
    const float* __restrict__ pts, const float2* __restrict__ txy,
    const float2* __restrict__ txz, const float2* __restrict__ tyz,
    float* __restrict__ out, LvlC lc, int n)
{
  int i = blockIdx.x * 256 + threadIdx.x;
  if (i >= n) return;
  float u0 = (pts[3 * i + 0] + 1.f) * .5f;
  float u1 = (pts[3 * i + 1] + 1.f) * .5f;
  float u2 = (pts[3 * i + 2] + 1.f) * .5f;
  const float ua[3] = {u0, u0, u1}, ub[3] = {u1, u2, u2};
  const float2* tabs[3] = {txy, txz, tyz};
  float acc[32];
#pragma unroll
  for (int j = 0; j < 32; ++j) acc[j] = 0.f;
#pragma unroll
  for (int l = 0; l < NLEV; ++l) {
    const float sc = lc.scale[l];
    const unsigned o = lc.offset[l], s = lc.stride[l];
#pragma unroll
    for (int p = 0; p < 3; ++p) {
      const float2* t = tabs[p];
      float px = ua[p] * sc + .5f, py = ub[p] * sc + .5f;
      float fx = floorf(px), fy = floorf(py);
      float rx = px - fx, ry = py - fy;
      unsigned x0 = (unsigned)fx, y0 = (unsigned)fy;
      float w00 = (1.f - rx) * (1.f - ry), w10 = rx * (1.f - ry);
      float w01 = (1.f - rx) * ry,          w11 = rx * ry;
      float2 f00, f10, f01, f11;
      if (l >= HASH_START) {
        unsigned hy0 = y0 * HASH_PRIME, hy1 = hy0 + HASH_PRIME;
        f00 = t[o + ((x0 ^ hy0) & HMASK)];
        f10 = t[o + (((x0 + 1u) ^ hy0) & HMASK)];
        f01 = t[o + ((x0 ^ hy1) & HMASK)];
        f11 = t[o + (((x0 + 1u) ^ hy1) & HMASK)];
      } else {
        unsigned i00 = x0 + y0 * s;
        float4 r0 = *reinterpret_cast<const float4*>(t + o + i00);
        float4 r1 = *reinterpret_cast<const float4*>(t + o + i00 + s);
        f00 = make_float2(r0.x, r0.y); f10 = make_float2(r0.z, r0.w);
        f01 = make_float2(r1.x, r1.y); f11 = make_float2(r1.z, r1.w);
      }
      acc[2 * l + 0] += w00 * f00.x + w10 * f10.x + w01 * f01.x + w11 * f11.x;
      acc[2 * l + 1] += w00 * f00.y + w10 * f10.y + w01 * f01.y + w11 * f11.y;
    }
  }
  float4* o4 = (float4*)(out + (size_t)i * 32);
#pragma unroll
  for (int j = 0; j < 8; ++j)
    o4[j] = make_float4(acc[4 * j], acc[4 * j + 1], acc[4 * j + 2], acc[4 * j + 3]);
}

static unsigned compute_levels(LvlC* lc)
{
  // Mirrors Python _level_constants() with identical double-precision ops.
  const double pls = std::pow(2.0, std::log2(2048.0 / 16.0) / 15.0);
  unsigned long long off = 0;
  for (int l = 0; l < NLEV; ++l) {
    double s = 16.0 * std::pow(pls, (double)l) - 1.0;
    lc->scale[l] = (float)s;
    long long r = (long long)std::ceil(s) + 1;
    long long dense = (r + 1) * (r + 1);
    long long sz = dense < (1LL << 19) ? dense : (1LL << 19);
    sz = ((sz + 7) / 8) * 8;
    lc->stride[l] = (unsigned)(r + 1);
    lc->offset[l] = (unsigned)off;
    off += (unsigned long long)sz;
  }
  return (unsigned)off;
}

extern "C" void kernel_launch(void* const* d_in, const int* in_sizes, int n_in,
                              void* d_out, int out_size, void* d_ws, size_t ws_size,
                              hipStream_t stream) {
  const float*  pts = (const float*)d_in[0];
  const float2* txy = (const float2*)d_in[1];
  const float2* txz = (const float2*)d_in[2];
  const float2* tyz = (const float2*)d_in[3];
  float* out = (float*)d_out;
  int n = in_sizes[0] / 3;  // 1048576 points

  LvlC lc;
  unsigned total = compute_levels(&lc);

  size_t tab_bytes = (size_t)3 * total * 4;
  size_t tab_al = (tab_bytes + 255) & ~(size_t)255;
  size_t need = tab_al + (size_t)4 * n * 4;

  bool ok = (n % 512 == 0) && (lc.offset[6] == LDS_WORDS) && (ws_size >= need);
  for (int l = HASH_START; l < NLEV; ++l) {
    unsigned sz = ((l + 1 < NLEV) ? lc.offset[l + 1] : total) - lc.offset[l];
    ok = ok && (sz == (1u << 19));
  }

  int block = 256;
  int grid = (n + block - 1) / block;
  if (!ok) {
    k_fallback<<<grid, block, 0, stream>>>(pts, txy, txz, tyz, out, lc, n);
    return;
  }

  unsigned* tab16 = (unsigned*)d_ws;
  unsigned* slices = (unsigned*)((char*)d_ws + tab_al);  // 4 x n (levels 12..15)

  int half = n / 2;
  int gridh = half / block;

  k_convert<<<2048, 256, 0, stream>>>(txy, txz, tyz, tab16, total);
  for (int l = HASH_START; l < NLEV; ++l)
    k_hash_lvl<<<gridh, block, 0, stream>>>(pts, tab16, slices + (size_t)(l - 12) * n,
                                            lc.scale[l], lc.offset[l], total, half);
  k_final<<<n / 512, 512, 0, stream>>>(pts, tab16, slices, out, lc, total, n);
}